// Round 8
// baseline (81.339 us; speedup 1.0000x reference)
//
#include <hip/hip_runtime.h>
#include <math.h>

#define NPTS  8192
#define BATCH 2
#define GY    32                               // candidate chunks
#define CJ    (NPTS / GY)                      // 256 candidates per chunk
#define IPT   4                                // points per thread (register-resident)
#define TPB   256
#define NSLOT (2 * BATCH * NPTS)               // 32768 point slots (dir x batch x point)
#define GX    (NSLOT / (TPB * IPT))            // 32 -> 1024 blocks = 4/CU, 16 waves/CU

typedef float v2f __attribute__((ext_vector_type(2)));
typedef float v4f __attribute__((ext_vector_type(4)));

// R8 = single-variable A/B vs R5: identical compute (IPT=4, CJ=256, v4f LDS,
// min3 inner loop), ONLY the tail changes: plain coalesced stores to a
// g-major partial matrix instead of device-scope atomicMin. Distinguishes
// "atomics cost ~14us" (Theory A) from "common core is the floor" (Theory B).
__global__ __launch_bounds__(TPB) void chamfer_pairs(
    const float* __restrict__ pred, const float* __restrict__ gt,
    float* __restrict__ part)
{
    __shared__ v4f xs4[CJ / 4], ys4[CJ / 4], zs4[CJ / 4], qs4[CJ / 4];

    const int base  = blockIdx.x * (TPB * IPT);   // global point-slot base
    const int dir   = base >> 14;                 // 0: points=gt (dist1), 1: points=pred (dist2)
    const int b     = (base >> 13) & 1;
    const int ibase = base & (NPTS - 1);

    const float* pts  = (dir == 0 ? gt : pred) + (size_t)b * NPTS * 3;
    const float* cand = (dir == 0 ? pred : gt) + (size_t)b * NPTS * 3;

    // stage candidate chunk: (x, y, z, q = 0.5*|c|^2), SoA for ds_read_b128
    const int j0 = blockIdx.y * CJ;
    {
        float* xs = (float*)xs4; float* ys = (float*)ys4;
        float* zs = (float*)zs4; float* qs = (float*)qs4;
        for (int jj = threadIdx.x; jj < CJ; jj += TPB) {
            float x = cand[(size_t)(j0 + jj) * 3 + 0];
            float y = cand[(size_t)(j0 + jj) * 3 + 1];
            float z = cand[(size_t)(j0 + jj) * 3 + 2];
            xs[jj] = x; ys[jj] = y; zs[jj] = z;
            qs[jj] = 0.5f * (x * x + y * y + z * z);
        }
    }

    float px[IPT], py[IPT], pz[IPT], m[IPT];
#pragma unroll
    for (int k = 0; k < IPT; ++k) {
        int i = ibase + threadIdx.x + k * TPB;
        px[k] = pts[(size_t)i * 3 + 0];
        py[k] = pts[(size_t)i * 3 + 1];
        pz[k] = pts[(size_t)i * 3 + 2];
        m[k]  = 3.0e38f;
    }
    __syncthreads();

    // min over candidates of t = q - p.c  (d^2 = |p|^2 + 2t)
    // per 4 candidates per point: 6 v_pk_fma_f32 + 2 v_min3_f32 = 2.0 slots/pair
#pragma unroll 4
    for (int j = 0; j < CJ / 4; ++j) {
        v4f cx = xs4[j], cy = ys4[j], cz = zs4[j], cq = qs4[j];  // broadcast b128
        v2f cxa = cx.xy, cxb = cx.zw, cya = cy.xy, cyb = cy.zw;
        v2f cza = cz.xy, czb = cz.zw, cqa = cq.xy, cqb = cq.zw;
#pragma unroll
        for (int k = 0; k < IPT; ++k) {
            v2f ta = cqa - cxa * px[k];
            ta = ta - cya * py[k];
            ta = ta - cza * pz[k];
            v2f tb = cqb - cxb * px[k];
            tb = tb - cyb * py[k];
            tb = tb - czb * pz[k];
            m[k] = fminf(fminf(m[k], ta.x), ta.y);   // -> v_min3_f32
            m[k] = fminf(fminf(m[k], tb.x), tb.y);   // -> v_min3_f32
        }
    }

    // plain coalesced stores (the ONLY change vs R5)
    float* prow = part + (size_t)blockIdx.y * NSLOT + base;
#pragma unroll
    for (int k = 0; k < IPT; ++k) {
        float gsq = fmaf(px[k], px[k], fmaf(py[k], py[k], pz[k] * pz[k]));
        float d2  = fmaxf(fmaf(2.0f, m[k], gsq), 0.0f);
        prow[k * TPB + threadIdx.x] = d2;
    }
}

// Phase 2: 32-way min across chunks + sqrt + sum. 256 blocks x 128 thr,
// each thread: 32 fully-independent strided loads (one waitcnt), coalesced
// 512B per wave-load. Kernel boundary provides coherence for plain stores.
__global__ __launch_bounds__(128) void chamfer_reduce(
    const float* __restrict__ part, float* __restrict__ out)
{
    const int s = blockIdx.x * 128 + threadIdx.x;
    float v[GY];
#pragma unroll
    for (int g = 0; g < GY; ++g)
        v[g] = part[(size_t)g * NSLOT + s];

    float m = v[0];
#pragma unroll
    for (int g = 1; g < GY; ++g) m = fminf(m, v[g]);

    float sum = sqrtf(m);
    for (int off = 32; off > 0; off >>= 1)
        sum += __shfl_down(sum, off, 64);

    __shared__ float ws[2];
    const int wave = threadIdx.x >> 6, lane = threadIdx.x & 63;
    if (lane == 0) ws[wave] = sum;
    __syncthreads();
    if (threadIdx.x == 0)
        atomicAdd(out, (ws[0] + ws[1]) * (1.0f / (float)(BATCH * NPTS)));
}

extern "C" void kernel_launch(void* const* d_in, const int* in_sizes, int n_in,
                              void* d_out, int out_size, void* d_ws, size_t ws_size,
                              hipStream_t stream) {
    const float* pred = (const float*)d_in[0];
    const float* gt   = (const float*)d_in[1];
    float* part = (float*)d_ws;                 // GY * NSLOT * 4B = 4.2 MB

    hipMemsetAsync(d_out, 0, sizeof(float), stream);

    dim3 grid(GX, GY);
    chamfer_pairs<<<grid, TPB, 0, stream>>>(pred, gt, part);
    chamfer_reduce<<<NSLOT / 128, 128, 0, stream>>>(part, (float*)d_out);
}